// Round 6
// baseline (267.942 us; speedup 1.0000x reference)
//
#include <hip/hip_runtime.h>
#include <math.h>

// Problem constants
#define N_TOK 131072   // 32*64*64 tokens
#define D     64       // embedding dim
#define K     1024     // codebook size

// Output layout (floats, concatenated in reference return order):
#define OUT_LOSS  8388608
#define OUT_IDX   8388609
#define OUT_PERP  8519681

// ws layout (bytes):
//   0        counts  u32[1024]
//   4096     enorm   f32[1024]  np-exact ||e||^2
//   8192     sinit   f32[1024]  fp64-accurate ||e||^2 (screen C-init)
//   12288    sse     f32
//   12292    rcnt    u32        rescue-list counter
//   16384    w_hi    s16[65536] bf16 hi split of w (128 KB)
//   147456   w_lo    s16[65536] bf16 lo split of w (128 KB)
//   278528   (unused; was win[])
//   802816   rlist   i32[131072] compacted rescue token ids

#define W_WINDOW 1e-4f

typedef short bf16x8 __attribute__((ext_vector_type(8)));
typedef float f32x4  __attribute__((ext_vector_type(4)));
typedef float vf16   __attribute__((ext_vector_type(16)));

// LDS byte-offset swizzle: XOR bits 4-6 with row bits (byte>>7)&7.
// Involution; applied on BOTH ds_write (staging) and ds_read (fragments).
#define SWZ(p) ((p) ^ ((((p) >> 7) & 7) << 4))

// ---------------------------------------------------------------------------
__device__ __forceinline__ float np_pairsum64(const float* sq) {
    float r[8];
#pragma unroll
    for (int j = 0; j < 8; ++j) r[j] = sq[j];
#pragma unroll
    for (int i = 8; i < 64; i += 8) {
#pragma unroll
        for (int j = 0; j < 8; ++j) r[j] = __fadd_rn(r[j], sq[i + j]);
    }
    return __fadd_rn(
        __fadd_rn(__fadd_rn(r[0], r[1]), __fadd_rn(r[2], r[3])),
        __fadd_rn(__fadd_rn(r[4], r[5]), __fadd_rn(r[6], r[7])));
}

__device__ __forceinline__ short bf16_trunc(float f) {
    return (short)(__float_as_uint(f) >> 16);
}
__device__ __forceinline__ float bf16_up(short s) {
    return __uint_as_float(((unsigned)(unsigned short)s) << 16);
}

// ---------------------------------------------------------------------------
__global__ void vq_prep(const float* __restrict__ w,
                        float* __restrict__ enorm,
                        float* __restrict__ sinit,
                        short* __restrict__ w_hi,
                        short* __restrict__ w_lo,
                        unsigned* __restrict__ counts,
                        float* __restrict__ sse,
                        unsigned* __restrict__ rcnt) {
    int k = blockIdx.x * blockDim.x + threadIdx.x;
    if (k < K) {
        const float* wr = w + (size_t)k * D;
        float sq[D];
        double acc = 0.0;
#pragma unroll
        for (int i = 0; i < D; ++i) {
            float v = wr[i];
            sq[i] = __fmul_rn(v, v);
            acc += (double)v * (double)v;
            short hi = bf16_trunc(v);
            float res = v - bf16_up(hi);
            short lo = bf16_trunc(res);
            w_hi[(size_t)k * D + i] = hi;
            w_lo[(size_t)k * D + i] = lo;
        }
        enorm[k] = np_pairsum64(sq);
        sinit[k] = (float)acc;
        counts[k] = 0u;
    }
    if (k == 0) { *sse = 0.f; *rcnt = 0u; }
}

// ---------------------------------------------------------------------------
// Screen + fused epilogue (round-5 math, bit-identical winner selection).
// Main loop: LDS-staged codebook chunks (double-buffered, swizzled), 12-MFMA
// hi/lo scheme, in-register top-2. sinit staged to LDS once (kills 64
// exposed global gathers per wave). Epilogue (was vq_epi): winners -> LDS,
// counts/rlist/idx updates, then all 4 waves do the coalesced gather+copy+SSE
// for the block's 128 tokens. Saves the win[] round-trip, a launch, and runs
// the copy at 4 blocks/CU instead of epi's 2.
// ---------------------------------------------------------------------------
#define MFMA(A, B, C) __builtin_amdgcn_mfma_f32_16x16x32_bf16(A, B, C, 0, 0, 0)

__device__ __forceinline__ void tile_step(
    int code, const bf16x8 (&Ah)[2][2], const bf16x8 (&Al)[2][2],
    bf16x8 H0, bf16x8 H1, bf16x8 L0, bf16x8 L1, float si,
    float (&m1)[8], float (&m2)[8], int (&i1)[8]) {
    f32x4 C0 = {si, si, si, si};
    f32x4 C1 = {si, si, si, si};
    C0 = MFMA(Ah[0][0], H0, C0); C0 = MFMA(Ah[0][1], H1, C0);
    C0 = MFMA(Ah[0][0], L0, C0); C0 = MFMA(Ah[0][1], L1, C0);
    C0 = MFMA(Al[0][0], H0, C0); C0 = MFMA(Al[0][1], H1, C0);
    C1 = MFMA(Ah[1][0], H0, C1); C1 = MFMA(Ah[1][1], H1, C1);
    C1 = MFMA(Ah[1][0], L0, C1); C1 = MFMA(Ah[1][1], L1, C1);
    C1 = MFMA(Al[1][0], H0, C1); C1 = MFMA(Al[1][1], H1, C1);
#pragma unroll
    for (int r = 0; r < 4; ++r) {
        {
            float c = C0[r];
            // med3(m1,m2,c) == min(m2, max(m1,c)) given m1<=m2 (exact select)
            m2[r] = __builtin_amdgcn_fmed3f(m1[r], m2[r], c);
            bool lt = c < m1[r];
            i1[r] = lt ? code : i1[r];
            m1[r] = fminf(m1[r], c);
        }
        {
            float c = C1[r];
            m2[4 + r] = __builtin_amdgcn_fmed3f(m1[4 + r], m2[4 + r], c);
            bool lt = c < m1[4 + r];
            i1[4 + r] = lt ? code : i1[4 + r];
            m1[4 + r] = fminf(m1[4 + r], c);
        }
    }
}

__global__ __launch_bounds__(256, 4)
void vq_screen(const float* __restrict__ x,
               const float* __restrict__ sinit,
               const short* __restrict__ w_hi,
               const short* __restrict__ w_lo,
               const float* __restrict__ w,
               float* __restrict__ out,
               unsigned* __restrict__ counts,
               float* __restrict__ sse,
               int* __restrict__ rlist,
               unsigned* __restrict__ rcnt) {
    const int tid  = threadIdx.x;
    const int lane = tid & 63;
    const int wv   = __builtin_amdgcn_readfirstlane(tid >> 6);
    const int quad = lane >> 4;
    const int col  = lane & 15;
    const int tokWave = blockIdx.x * 128 + wv * 32;

    // [buf][hi/lo][64 codes * 64 dims] = 32 KB
    __shared__ short sB[2][2][4096];
    __shared__ float sS[1024];   // sinit staged once (4 KB)
    __shared__ int   smw[128];   // per-block winner table for fused epilogue

    bf16x8 Ah[2][2], Al[2][2];
#pragma unroll
    for (int mt = 0; mt < 2; ++mt) {
#pragma unroll
        for (int ks = 0; ks < 2; ++ks) {
            const float4* ap = (const float4*)(x + (size_t)(tokWave + mt * 16 + col) * D
                                               + ks * 32 + quad * 8);
            float4 u0 = ap[0], u1 = ap[1];
            float f[8] = {u0.x, u0.y, u0.z, u0.w, u1.x, u1.y, u1.z, u1.w};
            bf16x8 h, l;
#pragma unroll
            for (int j = 0; j < 8; ++j) {
                float v = -2.0f * f[j];
                short hi = bf16_trunc(v);
                float res = v - bf16_up(hi);
                h[j] = hi;
                l[j] = bf16_trunc(res);
            }
            Ah[mt][ks] = h;
            Al[mt][ks] = l;
        }
    }

    float m1[8], m2[8];
    int   i1[8];
#pragma unroll
    for (int s = 0; s < 8; ++s) { m1[s] = INFINITY; m2[s] = INFINITY; i1[s] = 0; }

    // Staging geometry: chunk = 64 codes = 8192 B per array (hi, lo).
    const int  p0 = tid * 16;
    const int  p1 = p0 + 4096;
    const char* gh = (const char*)w_hi;
    const char* gl = (const char*)w_lo;

    // Initial stage: chunk 0 -> buf 0, plus sinit -> LDS.
    {
        float4 g0 = *(const float4*)(gh + p0);
        float4 g1 = *(const float4*)(gh + p1);
        float4 g2 = *(const float4*)(gl + p0);
        float4 g3 = *(const float4*)(gl + p1);
        float4 s4 = *(const float4*)(sinit + tid * 4);
        char* lh = (char*)&sB[0][0][0];
        char* ll = (char*)&sB[0][1][0];
        *(float4*)(lh + SWZ(p0)) = g0;
        *(float4*)(lh + SWZ(p1)) = g1;
        *(float4*)(ll + SWZ(p0)) = g2;
        *(float4*)(ll + SWZ(p1)) = g3;
        *(float4*)(&sS[tid * 4]) = s4;
    }
    __syncthreads();

    for (int c = 0; c < 16; ++c) {
        const int buf = c & 1;
        const bool pf = (c < 15);
        float4 g0, g1, g2, g3;
        if (pf) {
            const size_t cb = (size_t)(c + 1) * 8192;
            g0 = *(const float4*)(gh + cb + p0);
            g1 = *(const float4*)(gh + cb + p1);
            g2 = *(const float4*)(gl + cb + p0);
            g3 = *(const float4*)(gl + cb + p1);
        }

        const char* lh = (const char*)&sB[buf][0][0];
        const char* ll = (const char*)&sB[buf][1][0];
#pragma unroll
        for (int tl = 0; tl < 4; ++tl) {
            const int r_ = tl * 16 + col;          // code row within chunk
            const int b0 = r_ * 128 + quad * 16;
            const int b1 = b0 + 64;
            bf16x8 H0 = *(const bf16x8*)(lh + SWZ(b0));
            bf16x8 H1 = *(const bf16x8*)(lh + SWZ(b1));
            bf16x8 L0 = *(const bf16x8*)(ll + SWZ(b0));
            bf16x8 L1 = *(const bf16x8*)(ll + SWZ(b1));
            const int tile = c * 4 + tl;
            const float si = sS[tile * 16 + col];
            tile_step(tile * 16 + col, Ah, Al, H0, H1, L0, L1, si, m1, m2, i1);
        }

        if (pf) {
            char* dh = (char*)&sB[buf ^ 1][0][0];
            char* dl = (char*)&sB[buf ^ 1][1][0];
            *(float4*)(dh + SWZ(p0)) = g0;
            *(float4*)(dh + SWZ(p1)) = g1;
            *(float4*)(dl + SWZ(p0)) = g2;
            *(float4*)(dl + SWZ(p1)) = g3;
        }
        __syncthreads();
    }

#pragma unroll
    for (int s = 0; s < 8; ++s) {
#pragma unroll
        for (int msk = 1; msk <= 8; msk <<= 1) {
            float om1 = __shfl_xor(m1[s], msk, 64);
            int   oi1 = __shfl_xor(i1[s], msk, 64);
            float om2 = __shfl_xor(m2[s], msk, 64);
            float nm2 = fminf(fmaxf(m1[s], om1), fminf(m2[s], om2));
            bool  take = om1 < m1[s];
            m1[s] = take ? om1 : m1[s];
            i1[s] = take ? oi1 : i1[s];
            m2[s] = nm2;
        }
    }

    // ---- fused epilogue phase A: winners -> LDS, counts/rlist/idx ----
    if (col == 0) {
#pragma unroll
        for (int s = 0; s < 8; ++s) {
            int tl = (s >> 2) * 16 + quad * 4 + (s & 3);     // 0..31 in wave
            int tok = tokWave + tl;
            bool resc = (m2[s] <= m1[s] + W_WINDOW);
            if (resc) {
                unsigned u = atomicAdd(rcnt, 1u);
                rlist[u] = tok;
                smw[wv * 32 + tl] = -1;
            } else {
                atomicAdd(&counts[i1[s]], 1u);
                out[OUT_IDX + tok] = (float)i1[s];
                smw[wv * 32 + tl] = i1[s];
            }
        }
    }
    __syncthreads();

    // ---- fused epilogue phase B: coalesced gather+copy+SSE ----
    const int sub = lane >> 4;          // token within 4-token pass
    const int fi  = lane & 15;          // float4 index within 64-float row
    float err = 0.f;
#pragma unroll
    for (int p = 0; p < 8; ++p) {
        const int tl  = wv * 32 + p * 4 + sub;               // 0..127
        const int tok = blockIdx.x * 128 + tl;
        const int wi2 = smw[tl];
        if (wi2 >= 0) {
            float4 q  = ((const float4*)(w + (size_t)wi2 * D))[fi];
            float4 xv = ((const float4*)(x + (size_t)tok * D))[fi];
            float e0 = q.x - xv.x, e1 = q.y - xv.y;
            float e2 = q.z - xv.z, e3 = q.w - xv.w;
            err = fmaf(e0, e0, err);
            err = fmaf(e1, e1, err);
            err = fmaf(e2, e2, err);
            err = fmaf(e3, e3, err);
            ((float4*)(out + (size_t)tok * D))[fi] = q;
        }
    }
#pragma unroll
    for (int o = 32; o > 0; o >>= 1) err += __shfl_down(err, o, 64);
    if (lane == 0) atomicAdd(sse, err);
}
#undef MFMA

// ---------------------------------------------------------------------------
// Rescue v3 (round-5): 512 threads = 8 waves (2 waves/SIMD -> 256-VGPR
// budget, no spill), wave wv scans codes [wv*128, wv*128+128) ascending.
// LDS first-min combine over 8 chunks ascending == np.argmin.
// ---------------------------------------------------------------------------
#define XR(d) ((d) < 16 ? xa[(d) & 15] : (d) < 32 ? xb[(d) & 15] \
              : (d) < 48 ? xc[(d) & 15] : xd[(d) & 15])

__global__ __launch_bounds__(512, 2)
void vq_rescue(const float* __restrict__ x,
               const float* __restrict__ w,
               const float* __restrict__ enorm,
               float* __restrict__ out,
               unsigned* __restrict__ counts,
               float* __restrict__ sse,
               const int* __restrict__ rlist,
               const unsigned* __restrict__ rcnt) {
    const int lane = threadIdx.x & 63;
    const int wv   = __builtin_amdgcn_readfirstlane(threadIdx.x >> 6);  // 0..7
    const unsigned n = *rcnt;

    __shared__ float sd[8][64];
    __shared__ int   si[8][64];

    for (unsigned g = blockIdx.x; g * 64u < n; g += 256u) {
        const unsigned slot = g * 64u + (unsigned)lane;
        const bool valid = slot < n;
        const int t = valid ? rlist[slot] : 0;

        const vf16* xp = (const vf16*)(x + (size_t)t * D);
        vf16 xa = xp[0], xb = xp[1], xc = xp[2], xd = xp[3];

        // Sx np-exact (8 accumulators, ascending blocks, pairwise tail).
        float Sx;
        {
            float r0, r1, r2, r3, r4, r5, r6, r7;
#define SQ(n) __fmul_rn(XR(n), XR(n))
            r0 = SQ(0); r1 = SQ(1); r2 = SQ(2); r3 = SQ(3);
            r4 = SQ(4); r5 = SQ(5); r6 = SQ(6); r7 = SQ(7);
#define ACC8(i)                                                           \
            r0 = __fadd_rn(r0, SQ(8*(i)+0)); r1 = __fadd_rn(r1, SQ(8*(i)+1)); \
            r2 = __fadd_rn(r2, SQ(8*(i)+2)); r3 = __fadd_rn(r3, SQ(8*(i)+3)); \
            r4 = __fadd_rn(r4, SQ(8*(i)+4)); r5 = __fadd_rn(r5, SQ(8*(i)+5)); \
            r6 = __fadd_rn(r6, SQ(8*(i)+6)); r7 = __fadd_rn(r7, SQ(8*(i)+7));
            ACC8(1) ACC8(2) ACC8(3) ACC8(4) ACC8(5) ACC8(6) ACC8(7)
            Sx = __fadd_rn(
                __fadd_rn(__fadd_rn(r0, r1), __fadd_rn(r2, r3)),
                __fadd_rn(__fadd_rn(r4, r5), __fadd_rn(r6, r7)));
#undef ACC8
#undef SQ
        }

        // np-exact scan of this wave's 128-code chunk (c ascending).
        float best = INFINITY;
        int   bidx = 0x7fffffff;
        const int c0 = wv * 128;
        for (int cc = 0; cc < 128; ++cc) {
            const int c = c0 + cc;
            const float* __restrict__ wr = w + (size_t)c * D;  // wave-uniform
            float a = 0.f;
#pragma unroll
            for (int d = 0; d < D; ++d) a = __fmaf_rn(wr[d], XR(d), a);
            float dist = __fsub_rn(__fadd_rn(Sx, enorm[c]), __fmul_rn(2.0f, a));
            bool lt = dist < best;  // strict <: first-min within chunk
            best = lt ? dist : best;
            bidx = lt ? c : bidx;
        }
        sd[wv][lane] = best;
        si[wv][lane] = bidx;
        __syncthreads();

        if (wv == 0) {
            float b  = sd[0][lane];
            int   bi = si[0][lane];
#pragma unroll
            for (int j = 1; j < 8; ++j) {
                float dj = sd[j][lane];
                bool  l  = dj < b;  // strict <: lower chunk (lower idx) wins ties
                b  = l ? dj : b;
                bi = l ? si[j][lane] : bi;
            }

            float err = 0.f;
            if (valid) {
                const float4* qr = (const float4*)(w + (size_t)bi * D);
                float4*       oq = (float4*)(out + (size_t)t * D);
#pragma unroll
                for (int i = 0; i < 16; ++i) {
                    float4 q = qr[i];
                    float e0 = q.x - XR(4 * i + 0);
                    float e1 = q.y - XR(4 * i + 1);
                    float e2 = q.z - XR(4 * i + 2);
                    float e3 = q.w - XR(4 * i + 3);
                    err = fmaf(e0, e0, err);
                    err = fmaf(e1, e1, err);
                    err = fmaf(e2, e2, err);
                    err = fmaf(e3, e3, err);
                    oq[i] = q;
                }
                out[OUT_IDX + t] = (float)bi;
                atomicAdd(&counts[bi], 1u);
            }
#pragma unroll
            for (int o = 32; o > 0; o >>= 1) err += __shfl_down(err, o, 64);
            if (lane == 0) atomicAdd(sse, err);
        }
        __syncthreads();
    }
}
#undef XR

// ---------------------------------------------------------------------------
__global__ void vq_fin(const unsigned* __restrict__ counts,
                       const float* __restrict__ sse,
                       float* __restrict__ out) {
    __shared__ float red[256];
    float s = 0.f;
    for (int k = threadIdx.x; k < K; k += 256) {
        float p = (float)counts[k] * (1.0f / (float)N_TOK);
        s += p * logf(p + 1e-10f);
    }
    red[threadIdx.x] = s;
    __syncthreads();
    for (int st = 128; st > 0; st >>= 1) {
        if (threadIdx.x < st) red[threadIdx.x] += red[threadIdx.x + st];
        __syncthreads();
    }
    if (threadIdx.x == 0) {
        out[OUT_PERP] = expf(-red[0]);
        out[OUT_LOSS] = 1.25f * (*sse) * (1.0f / 8388608.0f);  // (1+0.25)*MSE
    }
}

// ---------------------------------------------------------------------------
extern "C" void kernel_launch(void* const* d_in, const int* in_sizes, int n_in,
                              void* d_out, int out_size, void* d_ws, size_t ws_size,
                              hipStream_t stream) {
    const float* x = (const float*)d_in[0];  // [32,64,64,64] fp32
    const float* w = (const float*)d_in[1];  // [1024,64] fp32
    float* out = (float*)d_out;

    char* ws = (char*)d_ws;
    unsigned* counts = (unsigned*)(ws + 0);
    float*    enorm  = (float*)(ws + 4096);
    float*    sinit  = (float*)(ws + 8192);
    float*    sse    = (float*)(ws + 12288);
    unsigned* rcnt   = (unsigned*)(ws + 12292);
    short*    w_hi   = (short*)(ws + 16384);
    short*    w_lo   = (short*)(ws + 147456);
    int*      rlist  = (int*)(ws + 802816);

    vq_prep<<<4, 256, 0, stream>>>(w, enorm, sinit, w_hi, w_lo, counts, sse, rcnt);
    vq_screen<<<N_TOK / 128, 256, 0, stream>>>(x, sinit, w_hi, w_lo, w, out,
                                               counts, sse, rlist, rcnt);
    vq_rescue<<<256, 512, 0, stream>>>(x, w, enorm, out, counts, sse, rlist, rcnt);
    vq_fin<<<1, 256, 0, stream>>>(counts, sse, out);
}